// Round 6
// baseline (388.975 us; speedup 1.0000x reference)
//
#include <hip/hip_runtime.h>

#define DEVFN __device__ __forceinline__

typedef __attribute__((ext_vector_type(8))) short short8;
typedef __attribute__((ext_vector_type(4))) float floatx4;
typedef unsigned short u16;
typedef unsigned int u32;

constexpr int B_   = 2;
constexpr int CIN  = 16;
constexpr int COUT = 16;
constexpr int T_   = 31;
constexpr int H_   = 128;
constexpr int W_   = 128;
constexpr int OC   = 6 * COUT;   // 96
constexpr int HW   = H_ * W_;    // 16384
constexpr int KVOL = CIN * 27;   // 432

// padded x layout [b][TP][cihalf(2)][HP][WP][8ci], fp16
constexpr int TP = T_ + 2;       // 33
constexpr int HP = H_ + 2;       // 130
constexpr int WP = W_ + 2;       // 130
constexpr int NPAD = B_ * TP * HP * WP;  // 1,115,400 positions

// A (weights) ws layout: [kd(3)][sl(5)][m(6)][quad(4)][n(16)][j(8)] fp16
constexpr int APH  = 5 * 6 * 4 * 16 * 8;   // 15360 elems per kd-phase
constexpr int ATOT = 3 * APH;              // 46080 elems
// B LDS slab per kd: [cihalf(2)][hh(6)][ww(130)][8ci]
constexpr int BHALF = 6 * WP * 8;          // 6240 elems per cihalf
constexpr int BSLAB = 2 * BHALF;           // 12480 elems
// epilogue transpose: 48 rows x 520
constexpr int TSTRIDE = 520;
constexpr int SMEMN = APH + BSLAB;         // 27840 elems (55680 B) >= 48*520

__constant__ const int KHt[9] = {0, 0, 0, 1, 1, 1, 2, 2, 2};
__constant__ const int KWt[9] = {0, 1, 2, 0, 1, 2, 0, 1, 2};

DEVFN float sigmoid_(float v) { return 1.f / (1.f + __expf(-v)); }
DEVFN float tanh_(float v)    { return 1.f - 2.f / (__expf(2.f * v) + 1.f); }

DEVFN u16 f2h(float v) {
  _Float16 h = (_Float16)v;
  u16 u; __builtin_memcpy(&u, &h, 2); return u;
}
DEVFN float h2f(u16 u) {
  _Float16 h; __builtin_memcpy(&h, &u, 2); return (float)h;
}

// ---------------------------------------------------------------------------
// Pre-kernel 1: fp32 x -> fp16, ci split into two 8-ci half-planes,
// zero-padded borders.  Dest: [b][tt][cihalf][hh][ww][8ci].
// ---------------------------------------------------------------------------
__global__ __launch_bounds__(256) void pad_x_f16(const float* __restrict__ x,
                                                 u16* __restrict__ xh) {
  const int idx = blockIdx.x * 256 + threadIdx.x;
  if (idx >= NPAD) return;
  int r = idx;
  const int ww = r % WP; r /= WP;
  const int hh = r % HP; r /= HP;
  const int tt = r % TP; const int b = r / TP;
  const bool in_ = (tt >= 1) & (tt <= T_) & (hh >= 1) & (hh <= H_) &
                   (ww >= 1) & (ww <= W_);
  const int ts = in_ ? tt - 1 : 0, hs = in_ ? hh - 1 : 0, ws = in_ ? ww - 1 : 0;
  const float* xp = x + ((size_t)b * CIN * T_ + ts) * HW + hs * W_ + ws;
  u32 ph[8];
#pragma unroll
  for (int ci = 0; ci < 16; ++ci) {
    const float v = in_ ? xp[ci * (T_ * HW)] : 0.f;
    const u16 hu = f2h(v);
    if (ci & 1) ph[ci >> 1] |= ((u32)hu) << 16;
    else        ph[ci >> 1] = hu;
  }
  const size_t pe = hh * (size_t)WP + ww;  // within an HP*WP half-plane
  const size_t pl = ((size_t)b * TP + tt) * 2;
  uint4* d0 = (uint4*)(xh + ((pl + 0) * HP * WP + pe) * 8);
  uint4* d1 = (uint4*)(xh + ((pl + 1) * HP * WP + pe) * 8);
  d0[0] = make_uint4(ph[0], ph[1], ph[2], ph[3]);
  d1[0] = make_uint4(ph[4], ph[5], ph[6], ph[7]);
}

// ---------------------------------------------------------------------------
// Pre-kernel 2: weights -> kd-major LDS-ready fp16 layout
// [kd][sl][m][quad][n][j]; k-within-step: loff = 2*sl+(quad>>1),
// ci = (quad&1)*8+j; slot loff==9 (pad) is zero.
// ---------------------------------------------------------------------------
__global__ __launch_bounds__(256) void reorder_w(const float* __restrict__ cw,
                                                 u16* __restrict__ wr) {
  const int idx = blockIdx.x * 256 + threadIdx.x;
  if (idx >= ATOT) return;
  const int j    = idx & 7;
  const int n    = (idx >> 3) & 15;
  const int quad = (idx >> 7) & 3;
  const int m    = (idx >> 9) % 6;
  const int rest = idx / 3072;
  const int sl   = rest % 5;
  const int kd   = rest / 5;
  const int loff = 2 * sl + (quad >> 1);
  const int ci   = (quad & 1) * 8 + j;
  const float v  = (loff < 9)
                     ? cw[(m * 16 + n) * KVOL + ci * 27 + kd * 9 + loff]
                     : 0.f;
  wr[idx] = f2h(v);
}

// ---------------------------------------------------------------------------
// Main conv: implicit GEMM, A AND B both staged in LDS. Block = 8 waves
// (512 thr) = 4 output h-rows x 128 w; 3 kd-phases, each stages the B
// slab (6 hh rows x 2 ci-halves) + A phase, then 5 k-steps x 24 MFMA
// purely from LDS. Gates stored PRE-ACTIVATION fp16 via LDS-transpose
// epilogue (16 B stores).
// ---------------------------------------------------------------------------
__global__ __launch_bounds__(512) void conv_mfma(
    const u16* __restrict__ xh, const u16* __restrict__ wr,
    const float* __restrict__ cb, u16* __restrict__ gates) {
  const int tid = threadIdx.x;
  const int lane = tid & 63, wv = tid >> 6;
  const int n = lane & 15, quad = lane >> 4;
  const int qhalf = quad >> 1, cihalf = quad & 1;
  const int hl = wv >> 1;            // output row within block (0..3)
  const int wbase = (wv & 1) * 64;   // wave's first w position
  const int h0 = blockIdx.x * 4;     // block's padded base h row
  const int bt = blockIdx.y;
  const int b = bt / T_, t = bt - b * T_;

  __shared__ u16 smem[SMEMN];
  u16* As = smem;
  u16* Bs = smem + APH;

  floatx4 acc[6][4];
#pragma unroll
  for (int m = 0; m < 6; ++m)
#pragma unroll
    for (int j = 0; j < 4; ++j) acc[m][j] = (floatx4)(0.f);

  for (int kd = 0; kd < 3; ++kd) {
    __syncthreads();
    // stage A phase (30720 B)
    const uint4* asrc = (const uint4*)(wr + kd * APH);
    for (int i = tid; i < APH / 8; i += 512) ((uint4*)As)[i] = asrc[i];
    // stage B slab (24960 B): two contiguous 12480 B half-plane strips
    const size_t pl = ((size_t)b * TP + (t + kd)) * 2;
    const u16* bsrc0 = xh + ((pl + 0) * HP + h0) * (size_t)WP * 8;
    const u16* bsrc1 = xh + ((pl + 1) * HP + h0) * (size_t)WP * 8;
    for (int i = tid; i < BSLAB / 8; i += 512) {
      const int c = (i >= BHALF / 8);
      const int rr = i - c * (BHALF / 8);
      ((uint4*)(Bs + c * BHALF))[rr] =
          ((const uint4*)(c ? bsrc1 : bsrc0))[rr];
    }
    __syncthreads();
#pragma unroll
    for (int sl = 0; sl < 5; ++sl) {
      const int lo = 2 * sl;
      const int hi = (lo + 1 < 9) ? lo + 1 : 8;
      const int kh = qhalf ? KHt[hi] : KHt[lo];
      const int kw = qhalf ? KWt[hi] : KWt[lo];
      const int baddr =
          ((cihalf * 6 + hl + kh) * WP + (wbase + n + kw)) * 8;
      short8 bh[4];
#pragma unroll
      for (int j = 0; j < 4; ++j)
        bh[j] = *(const short8*)(Bs + baddr + j * 128);
#pragma unroll
      for (int m = 0; m < 6; ++m) {
        const short8 a =
            *(const short8*)(As + (sl * 6 + m) * 512 + quad * 128 + n * 8);
#pragma unroll
        for (int j = 0; j < 4; ++j)
          acc[m][j] = __builtin_amdgcn_mfma_f32_16x16x32_f16(a, bh[j],
                                                             acc[m][j], 0, 0, 0);
      }
    }
  }

  // epilogue: bias + LDS transpose + 16 B stores, two 3-m-tile chunks
#pragma unroll
  for (int p = 0; p < 2; ++p) {
    __syncthreads();
#pragma unroll
    for (int mm = 0; mm < 3; ++mm) {
      const int m = p * 3 + mm;
#pragma unroll
      for (int r = 0; r < 4; ++r) {
        const int row = mm * 16 + quad * 4 + r;
        const float bias = cb[m * 16 + quad * 4 + r];
#pragma unroll
        for (int j = 0; j < 4; ++j)
          smem[row * TSTRIDE + hl * 128 + wbase + j * 16 + n] =
              f2h(acc[m][j][r] + bias);
      }
    }
    __syncthreads();
#pragma unroll
    for (int it = 0; it < 6; ++it) {
      const int u = it * 512 + tid;  // 0..3071
      const int row = u >> 6, col = u & 63;
      const short8 v = *(const short8*)(smem + row * TSTRIDE + col * 8);
      const int m = p * 3 + (row >> 4), c = row & 15;
      const int hh = blockIdx.x * 4 + (col >> 4);
      const int ww = (col & 15) * 8;
      *(short8*)(gates +
                 ((((m * B_ + b) * COUT + c) * T_ + t) * HW + hh * W_ + ww)) = v;
    }
  }
}

// ---------------------------------------------------------------------------
// Bidirectional SRU scan on pre-activation fp16 gates. 1 sp/thread, two
// sweeps: fwd packs htl as fp16 into 16 VGPRs; bwd re-reads Wx/X and
// emits out = htl + htr. Low VGPR -> full occupancy; activations here
// (memory-bound kernel, idle VALU).
// ---------------------------------------------------------------------------
__global__ __launch_bounds__(256) void sru_scan_kernel(
    const u16* __restrict__ g, float* __restrict__ out) {
  const int idx  = blockIdx.x * 256 + threadIdx.x;
  const int sp   = idx & (HW - 1);
  const int bc   = idx >> 14;
  const int base = bc * (T_ * HW) + sp;
  const int P    = B_ * COUT * T_ * HW;

  u32 hpk[16];
  float C = 0.f;
#pragma unroll
  for (int t = 0; t < T_; ++t) {
    const int o = base + t * HW;
    const float wx = tanh_(h2f(g[0 * P + o]));
    const float f  = sigmoid_(h2f(g[1 * P + o]));
    const float r  = sigmoid_(h2f(g[3 * P + o]));
    const float xv = tanh_(h2f(g[5 * P + o]));
    C = (t == 0) ? (1.f - f) : (f * C + (1.f - f) * wx);
    const float htl = r * C + (1.f - r) * xv;
    const u16 hb = f2h(htl);
    if (t & 1) hpk[t >> 1] |= ((u32)hb) << 16;
    else       hpk[t >> 1] = hb;
  }
  float C2 = 0.f;
#pragma unroll
  for (int t = T_ - 1; t >= 0; --t) {
    const int o = base + t * HW;
    const float f2 = sigmoid_(h2f(g[2 * P + o]));
    const float r2 = sigmoid_(h2f(g[4 * P + o]));
    const float wx = tanh_(h2f(g[0 * P + o]));
    const float xv = tanh_(h2f(g[5 * P + o]));
    C2 = (t == T_ - 1) ? (1.f - f2) : (f2 * C2 + (1.f - f2) * wx);
    const float htr = r2 * C2 + (1.f - r2) * xv;
    const float htl = h2f((u16)(hpk[t >> 1] >> ((t & 1) * 16)));
    out[o] = htl + htr;
  }
}

// ---------------------------------------------------------------------------
// Fallback direct conv (ws too small); pre-activation gates.
// ---------------------------------------------------------------------------
__global__ __launch_bounds__(256) void conv_gates_kernel(
    const float* __restrict__ x, const float* __restrict__ cw,
    const float* __restrict__ cb, u16* __restrict__ gates) {
  const int sp = blockIdx.x * 256 + threadIdx.x;
  const int oc = blockIdx.y;
  const int bt = blockIdx.z;
  const int b  = bt / T_;
  const int t  = bt - b * T_;
  const int h  = sp >> 7;
  const int wc = sp & (W_ - 1);

  __shared__ float wsh[KVOL];
  for (int i = threadIdx.x; i < KVOL; i += 256) wsh[i] = cw[oc * KVOL + i];
  __syncthreads();

  float acc = cb[oc];
  const float* xb = x + b * (CIN * T_ * HW);
  for (int ci = 0; ci < CIN; ++ci) {
    const float* xc = xb + ci * (T_ * HW);
#pragma unroll
    for (int kd = 0; kd < 3; ++kd) {
      const int tt = t + kd - 1;
      if ((unsigned)tt >= (unsigned)T_) continue;
      const float* xt = xc + tt * HW;
#pragma unroll
      for (int kh = 0; kh < 3; ++kh) {
        const int hh = h + kh - 1;
        if ((unsigned)hh >= (unsigned)H_) continue;
        const float* xr = xt + hh * W_;
        const float* wrp = &wsh[(ci * 3 + kd) * 9 + kh * 3];
        if (wc > 0)      acc += wrp[0] * xr[wc - 1];
        acc += wrp[1] * xr[wc];
        if (wc < W_ - 1) acc += wrp[2] * xr[wc + 1];
      }
    }
  }
  const int g = oc >> 4, c = oc & 15;
  const int off = (((g * B_ + b) * COUT + c) * T_ + t) * HW + sp;
  gates[off] = f2h(acc);
}

extern "C" void kernel_launch(void* const* d_in, const int* in_sizes, int n_in,
                              void* d_out, int out_size, void* d_ws,
                              size_t ws_size, hipStream_t stream) {
  (void)in_sizes; (void)n_in; (void)out_size;
  const float* x  = (const float*)d_in[0];
  const float* cw = (const float*)d_in[1];
  const float* cb = (const float*)d_in[2];
  float* out = (float*)d_out;

  const size_t planeElems = (size_t)B_ * COUT * T_ * HW;   // 16,252,928
  const size_t szGatesH = 6 * planeElems * sizeof(u16);    // 195,035,136
  const size_t szX      = (size_t)NPAD * 16 * sizeof(u16); // 35,692,800
  const size_t szW      = (size_t)ATOT * sizeof(u16);      // 92,160

  const int splitBlocks = (NPAD + 255) / 256;
  const int wBlocks     = (ATOT + 255) / 256;
  const dim3 gconv(H_ / 4, B_ * T_);              // 32 x 62, 512-thr blocks
  const int scanBlocks = (B_ * COUT * HW) / 256;  // 2048

  char* p = (char*)d_ws;
  u16* gates = (u16*)p;
  if (ws_size >= szGatesH + szX + szW) {
    u16* xhp = (u16*)(p + szGatesH);
    u16* wrp = (u16*)(p + szGatesH + szX);
    pad_x_f16<<<splitBlocks, 256, 0, stream>>>(x, xhp);
    reorder_w<<<wBlocks, 256, 0, stream>>>(cw, wrp);
    conv_mfma<<<gconv, 512, 0, stream>>>(xhp, wrp, cb, gates);
  } else {
    const dim3 gdir(HW / 256, OC, B_ * T_);
    conv_gates_kernel<<<gdir, 256, 0, stream>>>(x, cw, cb, gates);
  }
  sru_scan_kernel<<<scanBlocks, 256, 0, stream>>>(gates, out);
}